// Round 10
// baseline (178.314 us; speedup 1.0000x reference)
//
#include <hip/hip_runtime.h>
#include <hip/hip_bf16.h>
#include <cstdint>
#include <cstddef>

#define Bsz 4
#define Tseq 2048
#define Cdim 1024
#define Hh 16
#define Dh 64

typedef unsigned short u16;
typedef __bf16 bfx8 __attribute__((ext_vector_type(8)));
typedef float f32x4 __attribute__((ext_vector_type(4)));
typedef float f32x16 __attribute__((ext_vector_type(16)));
typedef unsigned short u16x8 __attribute__((ext_vector_type(8)));

#define AS1 __attribute__((address_space(1)))
#define AS3 __attribute__((address_space(3)))

// 0.125 (1/sqrt(64)) * log2(e): K pre-scale so softmax runs in exp2 domain
#define QSCALE 0.18033688f

__device__ __forceinline__ u16 f2b(float f) {
  union { float f; unsigned u; } x; x.f = f;
  unsigned r = x.u + 0x7FFFu + ((x.u >> 16) & 1u);
  return (u16)(r >> 16);
}
__device__ __forceinline__ float b2f(u16 b) {
  union { unsigned u; float f; } x; x.u = ((unsigned)b) << 16; return x.f;
}
__device__ __forceinline__ unsigned cvtpk(float lo, float hi) {
  unsigned r;
  asm("v_cvt_pk_bf16_f32 %0, %1, %2" : "=v"(r) : "v"(lo), "v"(hi));
  return r;
}
__device__ __forceinline__ void swap32(unsigned &a, unsigned &b) {
  asm("v_permlane32_swap_b32 %0, %1" : "+v"(a), "+v"(b));
}

// ---------------- elementwise f32 -> bf16 ----------------
__global__ __launch_bounds__(256) void cvt_f32_bf16(const float* __restrict__ in,
                                                    u16* __restrict__ out, int n4) {
  int i = blockIdx.x * 256 + threadIdx.x;
  if (i < n4) {
    const float4 v = reinterpret_cast<const float4*>(in)[i];
    ushort4 o;
    o.x = f2b(v.x); o.y = f2b(v.y); o.z = f2b(v.z); o.w = f2b(v.w);
    reinterpret_cast<ushort4*>(out)[i] = o;
  }
}

// ---------------- transpose + convert: in[R][Cn] f32 -> out[Cn][R] bf16 ----------------
__global__ __launch_bounds__(256) void transpose_cvt(const float* __restrict__ in,
                                                     u16* __restrict__ out, int R, int Cn) {
  __shared__ float tile[32][33];
  const int c0 = blockIdx.x * 32, r0 = blockIdx.y * 32;
  const int tx = threadIdx.x, ty = threadIdx.y;
  for (int i = ty; i < 32; i += 8)
    tile[i][tx] = in[(size_t)(r0 + i) * Cn + c0 + tx];
  __syncthreads();
  for (int i = ty; i < 32; i += 8)
    out[(size_t)(c0 + i) * R + r0 + tx] = f2b(tile[tx][i]);
}

// ---------------- qkv GEMM: 8-phase 256x256 schedule (m201-style, own ledger) ----------
// BM=BN=256, BK=64, 512 threads, 8 waves (2M x 4N), per-wave 128x64 (acc[8][4]).
// LDS: ring-4 of K-HALF tiles (kh = 32-wide) per matrix: 4 x [256 rows x 32k] x 2B
// = 16KB/slot, 128KB total -> 1 block/CU. Phases per K-tile: (kk,mh) in order
// 00,01,10,11 — 16 MFMA/phase; B-frags (4 reads) loaded on mh0, reused mh1;
// A-frags 4 reads/phase. Stage: tile t phase0 -> kh 2t+3 (A+B, 4 loads),
// phase2 -> kh 2t+4. Slot (g+3)&3 last read 2 phases earlier (behind >=1
// barrier) -> race-free. Boundary: vmcnt(4) once/K-tile (retires next tile's
// kh pair, issued >=4 phases earlier); tail vmcnt(0). Swizzle = r8-proven
// line-pair XOR (64B rows, 2-row 128B lines, slot p = s8 ^ (L&7)); linear
// global_load_lds dest + pre-swizzled per-lane global source.
// Epilogue (qkv): Q raw bf16; K third scaled by QSCALE; V third -> vt[bh][d][t].
__global__ __launch_bounds__(512, 2) void gemm_qkv(const u16* __restrict__ A, const u16* __restrict__ Bt,
                                                   const float* __restrict__ bias, u16* __restrict__ Cout,
                                                   u16* __restrict__ vtout,
                                                   int M, int N, int K) {
  __shared__ __align__(16) u16 Alds[4][8192];   // [slot][128 lines x 64 u16] = 16KB
  __shared__ __align__(16) u16 Blds[4][8192];
  const int tid = threadIdx.x;
  const int lane = tid & 63;
  const int wid = tid >> 6;           // 0..7
  const int nwgx = gridDim.x;         // N/256
  const int nwg = nwgx * gridDim.y;
  int lin = blockIdx.y * nwgx + blockIdx.x;
  lin = (lin & 7) * (nwg >> 3) + (lin >> 3);  // XCD-chunked swizzle (nwg%8==0)
  const int mbase = (lin / nwgx) * 256;
  const int nbase = (lin % nwgx) * 256;
  const int wm = wid & 1, wn = wid >> 1;

  // ---- staging source mapping (linear LDS dest, pre-swizzled global src) ----
  // dest u16 = j*4096 + wid*512 + lane*8 -> line L = j*64+wid*8+(lane>>3), p = lane&7;
  // s8 = p ^ (L&7) = (lane&7)^((lane>>3)&7); row = 2L+(s8>>2); kof = (s8&3)*8.
  const int s8 = (lane & 7) ^ ((lane >> 3) & 7);
  const int growb = wid * 16 + 2 * (lane >> 3) + (s8 >> 2);   // j=0 row
  const int skof = (s8 & 3) * 8;
  const u16* paw = A  + (size_t)(mbase + growb) * K + skof;
  const u16* pbw = Bt + (size_t)(nbase + growb) * K + skof;
  const size_t rstep128 = (size_t)128 * K;

  // ---- fragment read offsets (swizzled; mf/nf step = 1024B) ----
  const int rowA = wm * 128 + (lane & 15);
  const int LA = rowA >> 1;
  const int aoff = LA * 64 + ((((rowA & 1) << 2) + (lane >> 4)) ^ (LA & 7)) * 8;  // u16
  const int rowB = wn * 64 + (lane & 15);
  const int LB = rowB >> 1;
  const int boff = LB * 64 + ((((rowB & 1) << 2) + (lane >> 4)) ^ (LB & 7)) * 8;

  AS3 u16* aldsb = (AS3 u16*)&Alds[0][0];
  AS3 u16* bldsb = (AS3 u16*)&Blds[0][0];

  const f32x4 vzero = {0.f, 0.f, 0.f, 0.f};
  f32x4 acc[8][4];
  #pragma unroll
  for (int i = 0; i < 8; ++i)
    #pragma unroll
    for (int j = 0; j < 4; ++j) acc[i][j] = vzero;

  const int NT = K >> 6;     // 64-wide K-tiles
  const int KH = NT * 2;     // 32-wide K-halves

  auto stA = [&](int kh, int slot) {
    const u16* p = paw + kh * 32;
    __builtin_amdgcn_global_load_lds((AS1 void*)const_cast<u16*>(p),
                                     (AS3 void*)&Alds[slot][wid * 512], 16, 0, 0);
    __builtin_amdgcn_global_load_lds((AS1 void*)const_cast<u16*>(p + rstep128),
                                     (AS3 void*)&Alds[slot][4096 + wid * 512], 16, 0, 0);
  };
  auto stB = [&](int kh, int slot) {
    const u16* p = pbw + kh * 32;
    __builtin_amdgcn_global_load_lds((AS1 void*)const_cast<u16*>(p),
                                     (AS3 void*)&Blds[slot][wid * 512], 16, 0, 0);
    __builtin_amdgcn_global_load_lds((AS1 void*)const_cast<u16*>(p + rstep128),
                                     (AS3 void*)&Blds[slot][4096 + wid * 512], 16, 0, 0);
  };

  bfx8 af[4], bfv[4];
  auto rdA0 = [&](int slot) {  // mf 0..3
    AS3 u16* ap = aldsb + slot * 8192 + aoff;
    asm volatile("ds_read_b128 %0, %1"             : "=v"(af[0]) : "v"(ap));
    asm volatile("ds_read_b128 %0, %1 offset:1024" : "=v"(af[1]) : "v"(ap));
    asm volatile("ds_read_b128 %0, %1 offset:2048" : "=v"(af[2]) : "v"(ap));
    asm volatile("ds_read_b128 %0, %1 offset:3072" : "=v"(af[3]) : "v"(ap));
  };
  auto rdA1 = [&](int slot) {  // mf 4..7
    AS3 u16* ap = aldsb + slot * 8192 + aoff;
    asm volatile("ds_read_b128 %0, %1 offset:4096" : "=v"(af[0]) : "v"(ap));
    asm volatile("ds_read_b128 %0, %1 offset:5120" : "=v"(af[1]) : "v"(ap));
    asm volatile("ds_read_b128 %0, %1 offset:6144" : "=v"(af[2]) : "v"(ap));
    asm volatile("ds_read_b128 %0, %1 offset:7168" : "=v"(af[3]) : "v"(ap));
  };
  auto rdB = [&](int slot) {
    AS3 u16* bp = bldsb + slot * 8192 + boff;
    asm volatile("ds_read_b128 %0, %1"             : "=v"(bfv[0]) : "v"(bp));
    asm volatile("ds_read_b128 %0, %1 offset:1024" : "=v"(bfv[1]) : "v"(bp));
    asm volatile("ds_read_b128 %0, %1 offset:2048" : "=v"(bfv[2]) : "v"(bp));
    asm volatile("ds_read_b128 %0, %1 offset:3072" : "=v"(bfv[3]) : "v"(bp));
  };

  #define QKV_MFMA(MH)                                                                          \
    __builtin_amdgcn_s_setprio(1);                                                              \
    _Pragma("unroll")                                                                           \
    for (int i = 0; i < 4; ++i)                                                                 \
      _Pragma("unroll")                                                                         \
      for (int nf = 0; nf < 4; ++nf)                                                            \
        acc[(MH) * 4 + i][nf] =                                                                 \
            __builtin_amdgcn_mfma_f32_16x16x32_bf16(af[i], bfv[nf], acc[(MH) * 4 + i][nf],      \
                                                    0, 0, 0);                                   \
    __builtin_amdgcn_s_setprio(0);

  // ---- prologue: kh 0,1,2 (12 loads); retire kh0,kh1 (vmcnt(4) leaves kh2) ----
  stA(0, 0); stB(0, 0);
  stA(1, 1); stB(1, 1);
  stA(2, 2); stB(2, 2);
  asm volatile("s_waitcnt vmcnt(4)" ::: "memory");
  __builtin_amdgcn_s_barrier();

  for (int t = 0; t < NT; ++t) {
    const int g = 2 * t;
    const int sk0 = g & 3, sk1 = (g + 1) & 3;
    const int sp0 = (g + 3) & 3, sp1 = (g + 4) & 3;

    // ---- phase 0: kk0, mh0 ----
    rdA0(sk0); rdB(sk0);
    if (g + 3 < KH) { stA(g + 3, sp0); stB(g + 3, sp0); }
    __builtin_amdgcn_s_barrier();
    asm volatile("s_waitcnt lgkmcnt(0)" ::: "memory");
    __builtin_amdgcn_sched_barrier(0);
    QKV_MFMA(0);
    __builtin_amdgcn_s_barrier();

    // ---- phase 1: kk0, mh1 ----
    rdA1(sk0);
    __builtin_amdgcn_s_barrier();
    asm volatile("s_waitcnt lgkmcnt(0)" ::: "memory");
    __builtin_amdgcn_sched_barrier(0);
    QKV_MFMA(1);
    __builtin_amdgcn_s_barrier();

    // ---- phase 2: kk1, mh0 ----
    rdA0(sk1); rdB(sk1);
    if (g + 4 < KH) { stA(g + 4, sp1); stB(g + 4, sp1); }
    __builtin_amdgcn_s_barrier();
    asm volatile("s_waitcnt lgkmcnt(0)" ::: "memory");
    __builtin_amdgcn_sched_barrier(0);
    QKV_MFMA(0);
    __builtin_amdgcn_s_barrier();

    // ---- phase 3: kk1, mh1 ----
    rdA1(sk1);
    __builtin_amdgcn_s_barrier();
    asm volatile("s_waitcnt lgkmcnt(0)" ::: "memory");
    __builtin_amdgcn_sched_barrier(0);
    QKV_MFMA(1);

    // ---- K-tile boundary: counted retire of next tile's kh pair ----
    if (t + 1 < NT) {
      if (t + 2 < NT) { asm volatile("s_waitcnt vmcnt(4)" ::: "memory"); }
      else            { asm volatile("s_waitcnt vmcnt(0)" ::: "memory"); }
      __builtin_amdgcn_s_barrier();
    }
  }
  #undef QKV_MFMA

  // ---- epilogue (MODE1 semantics) ----
  float bv[4];
  #pragma unroll
  for (int nf = 0; nf < 4; ++nf) bv[nf] = bias[nbase + wn * 64 + nf * 16 + (lane & 15)];
  #pragma unroll
  for (int mf = 0; mf < 8; ++mf) {
    #pragma unroll
    for (int nf = 0; nf < 4; ++nf) {
      const int r0 = mbase + wm * 128 + mf * 16 + (lane >> 4) * 4;
      const int c  = nbase + wn * 64 + nf * 16 + (lane & 15);
      const int cb = nbase + wn * 64 + nf * 16;
      const float cscale = (cb >= 1024 && cb < 2048) ? QSCALE : 1.0f;
      float v[4];
      #pragma unroll
      for (int j = 0; j < 4; ++j) v[j] = (acc[mf][nf][j] + bv[nf]) * cscale;
      if (cb >= 2048) {
        const int hh = (c - 2048) >> 6, dd = (c - 2048) & 63;
        const int bb = r0 >> 11, tt = r0 & 2047;
        ushort4 pkd;
        pkd.x = f2b(v[0]); pkd.y = f2b(v[1]); pkd.z = f2b(v[2]); pkd.w = f2b(v[3]);
        *reinterpret_cast<ushort4*>(
            &vtout[(((size_t)bb * Hh + hh) * Dh + dd) * Tseq + tt]) = pkd;
      } else {
        #pragma unroll
        for (int j = 0; j < 4; ++j)
          Cout[(size_t)(r0 + j) * N + c] = f2b(v[j]);
      }
    }
  }
}

// ---------------- bf16 GEMM (proj): r14 ring-3 + split lgkm (proven, 166.6 config) ----
template<int MODE>
__global__ __launch_bounds__(512, 4) void gemm_bt(const u16* __restrict__ A, const u16* __restrict__ Bt,
                                                  const float* __restrict__ bias, void* __restrict__ Cout,
                                                  u16* __restrict__ vtout,
                                                  int M, int N, int K) {
  __shared__ __align__(16) u16 Alds[3][4096];   // [slot][64 lines x 64 u16]
  __shared__ __align__(16) u16 Blds[3][8192];   // [slot][128 lines x 64 u16]
  const int tid = threadIdx.x;
  const int lane = tid & 63;
  const int wid = tid >> 6;           // 0..7
  const int nwgx = gridDim.x;         // N/256
  const int nwg = nwgx * gridDim.y;
  int lin = blockIdx.y * nwgx + blockIdx.x;
  lin = (lin & 7) * (nwg >> 3) + (lin >> 3);  // XCD-chunked swizzle (nwg%8==0)
  const int mbase = (lin / nwgx) * 128;
  const int nbase = (lin % nwgx) * 256;
  const int wm = wid & 1, wn = wid >> 1;

  const int sLlow = lane >> 3;
  const int s8 = (lane & 7) ^ sLlow;
  const int srow = 2 * (wid * 8 + sLlow) + (s8 >> 2);
  const int skof = (s8 & 3) * 8;

  const u16* pa  = A  + (size_t)(mbase + srow) * K + skof;
  const u16* pb0 = Bt + (size_t)(nbase + srow) * K + skof;
  const u16* pb1 = pb0 + (size_t)128 * K;

  const int raA = wm * 64 + (lane & 15);
  const int LA = raA >> 1;
  const int pA = ((raA & 1) * 4 + (lane >> 4)) ^ (LA & 7);
  const int aoffw = LA * 64 + pA * 8;
  const int rbB = wn * 64 + (lane & 15);
  const int LB = rbB >> 1;
  const int pB = ((rbB & 1) * 4 + (lane >> 4)) ^ (LB & 7);
  const int boffw = LB * 64 + pB * 8;

  AS3 u16* aldsb = (AS3 u16*)&Alds[0][0];
  AS3 u16* bldsb = (AS3 u16*)&Blds[0][0];

  const f32x4 vzero = {0.f, 0.f, 0.f, 0.f};
  f32x4 acc[4][4];
  #pragma unroll
  for (int i = 0; i < 4; ++i)
    #pragma unroll
    for (int j = 0; j < 4; ++j) acc[i][j] = vzero;

  const int NT = K >> 5;

  auto stage = [&](int slot) {
    __builtin_amdgcn_global_load_lds((AS1 void*)const_cast<u16*>(pa),
                                     (AS3 void*)&Alds[slot][wid * 512], 16, 0, 0);
    __builtin_amdgcn_global_load_lds((AS1 void*)const_cast<u16*>(pb0),
                                     (AS3 void*)&Blds[slot][wid * 512], 16, 0, 0);
    __builtin_amdgcn_global_load_lds((AS1 void*)const_cast<u16*>(pb1),
                                     (AS3 void*)&Blds[slot][4096 + wid * 512], 16, 0, 0);
    pa += 32; pb0 += 32; pb1 += 32;
  };

  stage(0);
  stage(1);
  asm volatile("s_waitcnt vmcnt(3)" ::: "memory");
  __builtin_amdgcn_s_barrier();

  int slot = 0, pf = 2;
  for (int t = 0; t < NT; ++t) {
    if (t + 2 < NT) stage(pf);

    bfx8 af[4], bfv[4];
    {
      AS3 u16* ap = aldsb + slot * 4096 + aoffw;
      AS3 u16* bp = bldsb + slot * 8192 + boffw;
      asm volatile("ds_read_b128 %0, %1"             : "=v"(af[0])  : "v"(ap));
      asm volatile("ds_read_b128 %0, %1 offset:1024" : "=v"(af[1])  : "v"(ap));
      asm volatile("ds_read_b128 %0, %1"             : "=v"(bfv[0]) : "v"(bp));
      asm volatile("ds_read_b128 %0, %1 offset:1024" : "=v"(bfv[1]) : "v"(bp));
      asm volatile("ds_read_b128 %0, %1 offset:2048" : "=v"(bfv[2]) : "v"(bp));
      asm volatile("ds_read_b128 %0, %1 offset:3072" : "=v"(bfv[3]) : "v"(bp));
      asm volatile("ds_read_b128 %0, %1 offset:2048" : "=v"(af[2])  : "v"(ap));
      asm volatile("ds_read_b128 %0, %1 offset:3072" : "=v"(af[3])  : "v"(ap));
    }
    asm volatile("s_waitcnt lgkmcnt(2)" ::: "memory");
    __builtin_amdgcn_sched_barrier(0);

    __builtin_amdgcn_s_setprio(1);
    #pragma unroll
    for (int mf = 0; mf < 2; ++mf)
      #pragma unroll
      for (int nf = 0; nf < 4; ++nf)
        acc[mf][nf] = __builtin_amdgcn_mfma_f32_16x16x32_bf16(af[mf], bfv[nf], acc[mf][nf], 0, 0, 0);
    __builtin_amdgcn_s_setprio(0);

    asm volatile("s_waitcnt lgkmcnt(0)" ::: "memory");
    __builtin_amdgcn_sched_barrier(0);

    __builtin_amdgcn_s_setprio(1);
    #pragma unroll
    for (int mf = 2; mf < 4; ++mf)
      #pragma unroll
      for (int nf = 0; nf < 4; ++nf)
        acc[mf][nf] = __builtin_amdgcn_mfma_f32_16x16x32_bf16(af[mf], bfv[nf], acc[mf][nf], 0, 0, 0);
    __builtin_amdgcn_s_setprio(0);

    if (t + 2 < NT)      { asm volatile("s_waitcnt vmcnt(3)" ::: "memory"); }
    else if (t + 1 < NT) { asm volatile("s_waitcnt vmcnt(0)" ::: "memory"); }
    if (t + 1 < NT) __builtin_amdgcn_s_barrier();

    slot = (slot == 2) ? 0 : slot + 1;
    pf   = (pf == 2) ? 0 : pf + 1;
  }

  float bv[4];
  #pragma unroll
  for (int nf = 0; nf < 4; ++nf) bv[nf] = bias[nbase + wn * 64 + nf * 16 + (lane & 15)];
  #pragma unroll
  for (int mf = 0; mf < 4; ++mf) {
    #pragma unroll
    for (int nf = 0; nf < 4; ++nf) {
      const int r0 = mbase + wm * 64 + mf * 16 + (lane >> 4) * 4;
      const int c  = nbase + wn * 64 + nf * 16 + (lane & 15);
      const int cb = nbase + wn * 64 + nf * 16;
      const float cscale = (MODE == 1 && cb >= 1024 && cb < 2048) ? QSCALE : 1.0f;
      float v[4];
      #pragma unroll
      for (int j = 0; j < 4; ++j) v[j] = (acc[mf][nf][j] + bv[nf]) * cscale;
      if (MODE == 1 && cb >= 2048) {
        const int hh = (c - 2048) >> 6, dd = (c - 2048) & 63;
        const int bb = r0 >> 11, tt = r0 & 2047;
        ushort4 pkd;
        pkd.x = f2b(v[0]); pkd.y = f2b(v[1]); pkd.z = f2b(v[2]); pkd.w = f2b(v[3]);
        *reinterpret_cast<ushort4*>(
            &vtout[(((size_t)bb * Hh + hh) * Dh + dd) * Tseq + tt]) = pkd;
      } else {
        #pragma unroll
        for (int j = 0; j < 4; ++j) {
          if (MODE == 1) ((u16*)Cout)[(size_t)(r0 + j) * N + c] = f2b(v[j]);
          else           ((float*)Cout)[(size_t)(r0 + j) * N + c] = v[j];
        }
      }
    }
  }
}

// ---------------- causal flash attention: split-KV 8-wave, swapped-QK^T 32x32 ----------------
// EXACT r2 structure (four times measured 77.6-78.7us). FROZEN.
// FIXED-MAX softmax (m = 0): K pre-scaled by QSCALE.
#define ROWI(r) (((r) & 3) + 8 * ((r) >> 2))
__global__ __launch_bounds__(512, 4) void attn_fwd(const u16* __restrict__ qkv,
                                                   const u16* __restrict__ vt,
                                                   u16* __restrict__ aout) {
  __shared__ __align__(16) u16 Klds[4][64 * 64];   // [kt][d] swizzled, ring buf = tile&3
  __shared__ __align__(16) u16 Vtlds[4][64 * 64];  // [d][kt] swizzled
  const int tid = threadIdx.x;
  const int lane = tid & 63;
  const int wid = tid >> 6;   // 0..7
  const int qg = wid & 3;
  const int half = wid >> 2;  // 0: even tiles, 1: odd tiles
  const int lin = blockIdx.y * gridDim.x + blockIdx.x;  // 0..511
  const int bh = (lin & 7) * 8 + ((lin >> 3) & 7);
  const int qpair = lin >> 6;  // 0..7
  const int b = bh >> 4, h = bh & 15;
  const int hi4 = (lane & 32) >> 3;

  const int stg_row = lane >> 3;
  const int stg_srcslot = (lane & 7) ^ (stg_row & 7);

  const u16* gkbase = qkv + ((size_t)b * Tseq + wid * 8 + stg_row) * 3072
                      + 1024 + h * 64 + stg_srcslot * 8;
  const u16* gvbase = vt + ((size_t)bh * Dh + wid * 8 + stg_row) * Tseq + stg_srcslot * 8;

  float* Olds = reinterpret_cast<float*>(&Klds[0][0]);   // [qg][32r][64lane]
  float* Llds = reinterpret_cast<float*>(&Vtlds[0][0]);  // [qg][64lane]

  #pragma unroll 1
  for (int pass = 0; pass < 2; ++pass) {
    const int qtile = pass ? qpair : (15 - qpair);
    const int qwb = qtile * 128 + qg * 32;
    const int ntiles = qtile * 2 + 2;  // always even

    bfx8 qf[4];
    {
      const int qrow = qwb + (lane & 31);
      #pragma unroll
      for (int c = 0; c < 4; ++c) {
        const u16* src = qkv + (size_t)(b * Tseq + qrow) * 3072 + h * 64 + c * 16 + (hi4 << 1);
        qf[c] = *reinterpret_cast<const bfx8*>(src);
      }
    }

    float l_r = 0.f;
    f32x16 o0, o1;
    #pragma unroll
    for (int r = 0; r < 16; ++r) { o0[r] = 0.f; o1[r] = 0.f; }

    auto stageT = [&](int t) {
      const u16* gk = gkbase + (size_t)t * 64 * 3072;
      const u16* gv = gvbase + t * 64;
      __builtin_amdgcn_global_load_lds((AS1 void*)const_cast<u16*>(gk),
                                       (AS3 void*)&Klds[t & 3][wid * 512], 16, 0, 0);
      __builtin_amdgcn_global_load_lds((AS1 void*)const_cast<u16*>(gv),
                                       (AS3 void*)&Vtlds[t & 3][wid * 512], 16, 0, 0);
    };
    stageT(0);
    stageT(1);
    __syncthreads();

    for (int t = 0; t < ntiles; t += 2) {
      if (t + 2 < ntiles) stageT(t + 2);
      if (t + 3 < ntiles) stageT(t + 3);

      const int tt = t + half;
      const int kb = tt * 64;
      const int buf = tt & 3;
      if (kb <= qwb + 31) {
        f32x16 st0, st1;
        #pragma unroll
        for (int r = 0; r < 16; ++r) { st0[r] = 0.f; st1[r] = 0.f; }
        __builtin_amdgcn_s_setprio(1);
        #pragma unroll
        for (int c = 0; c < 4; ++c) {
          const int row0 = lane & 31;
          const int sl = (c * 2 + (lane >> 5)) ^ (row0 & 7);
          const bfx8 k0 = *reinterpret_cast<const bfx8*>(&Klds[buf][row0 * 64 + sl * 8]);
          const bfx8 k1 = *reinterpret_cast<const bfx8*>(&Klds[buf][(row0 + 32) * 64 + sl * 8]);
          st0 = __builtin_amdgcn_mfma_f32_32x32x16_bf16(k0, qf[c], st0, 0, 0, 0);
          st1 = __builtin_amdgcn_mfma_f32_32x32x16_bf16(k1, qf[c], st1, 0, 0, 0);
        }
        __builtin_amdgcn_s_setprio(0);

        if (kb + 63 > qwb) {
          const int qg_ = qwb + (lane & 31);
          #pragma unroll
          for (int r = 0; r < 16; ++r) {
            const int kt = kb + ROWI(r) + hi4;
            if (kt > qg_) st0[r] = -1e30f;
            if (kt + 32 > qg_) st1[r] = -1e30f;
          }
        }

        float rs = 0.f;
        #pragma unroll
        for (int r = 0; r < 16; ++r) { st0[r] = exp2f(st0[r]); rs += st0[r]; }
        #pragma unroll
        for (int r = 0; r < 16; ++r) { st1[r] = exp2f(st1[r]); rs += st1[r]; }
        rs += __shfl_xor(rs, 32);
        l_r += rs;

        bfx8 pf[4];
        #pragma unroll
        for (int tph = 0; tph < 2; ++tph) {
          #pragma unroll
          for (int c2 = 0; c2 < 2; ++c2) {
            const int rb = c2 * 8;
            float s0 = tph ? st1[rb + 0] : st0[rb + 0], s1 = tph ? st1[rb + 1] : st0[rb + 1];
            float s2 = tph ? st1[rb + 2] : st0[rb + 2], s3 = tph ? st1[rb + 3] : st0[rb + 3];
            float s4 = tph ? st1[rb + 4] : st0[rb + 4], s5 = tph ? st1[rb + 5] : st0[rb + 5];
            float s6 = tph ? st1[rb + 6] : st0[rb + 6], s7 = tph ? st1[rb + 7] : st0[rb + 7];
            unsigned w0 = cvtpk(s0, s1);
            unsigned w2 = cvtpk(s4, s5);
            swap32(w0, w2);
            unsigned w1 = cvtpk(s2, s3);
            unsigned w3 = cvtpk(s6, s7);
            swap32(w1, w3);
            union { unsigned w[4]; bfx8 v; } u;
            u.w[0] = w0; u.w[1] = w1; u.w[2] = w2; u.w[3] = w3;
            pf[tph * 2 + c2] = u.v;
          }
        }

        __builtin_amdgcn_s_setprio(1);
        #pragma unroll
        for (int c4 = 0; c4 < 4; ++c4) {
          const int vrow = lane & 31;
          const int sl = (c4 * 2 + (lane >> 5)) ^ (vrow & 7);
          const bfx8 vf0 = *reinterpret_cast<const bfx8*>(&Vtlds[buf][vrow * 64 + sl * 8]);
          const bfx8 vf1 = *reinterpret_cast<const bfx8*>(&Vtlds[buf][(vrow + 32) * 64 + sl * 8]);
          o0 = __builtin_amdgcn_mfma_f32_32x32x16_bf16(pf[c4], vf0, o0, 0, 0, 0);
          o1 = __builtin_amdgcn_mfma_f32_32x32x16_bf16(pf[c4], vf1, o1, 0, 0, 0);
        }
        __builtin_amdgcn_s_setprio(0);
      }

      __syncthreads();
    }

    if (half == 1) {
      Llds[qg * 64 + lane] = l_r;
      #pragma unroll
      for (int r = 0; r < 16; ++r) {
        Olds[qg * 2048 + r * 64 + lane]        = o0[r];
        Olds[qg * 2048 + (r + 16) * 64 + lane] = o1[r];
      }
    }
    __syncthreads();
    if (half == 0) {
      const float l1 = Llds[qg * 64 + lane];
      const float linv = 1.0f / (l_r + l1);
      #pragma unroll
      for (int r = 0; r < 16; ++r) {
        const int src = ROWI(r) + hi4;
        const float cr = __shfl(linv, src);
        const int q = qwb + src;
        const float v0 = (o0[r] + Olds[qg * 2048 + r * 64 + lane]) * cr;
        const float v1 = (o1[r] + Olds[qg * 2048 + (r + 16) * 64 + lane]) * cr;
        aout[(size_t)(b * Tseq + q) * 1024 + h * 64 + (lane & 31)]      = f2b(v0);
        aout[(size_t)(b * Tseq + q) * 1024 + h * 64 + 32 + (lane & 31)] = f2b(v1);
      }
    }
    __syncthreads();
  }
}

// ---------------- launcher ----------------
extern "C" void kernel_launch(void* const* d_in, const int* in_sizes, int n_in,
                              void* d_out, int out_size, void* d_ws, size_t ws_size,
                              hipStream_t stream) {
  const float* x      = (const float*)d_in[0];
  const float* W_qkv  = (const float*)d_in[1];
  const float* b_qkv  = (const float*)d_in[2];
  const float* W_proj = (const float*)d_in[3];
  const float* b_proj = (const float*)d_in[4];
  float* out = (float*)d_out;

  char* ws = (char*)d_ws;
  const size_t SZ_XB    = 16777216;   // [8192][1024] bf16 (x_bf16, later attn out)
  const size_t SZ_WQKV  = 6291456;    // [3072][1024] bf16
  const size_t SZ_WPROJ = 2097152;    // [1024][1024] bf16
  const size_t SZ_QKV   = 50331648;   // [8192][3072] bf16 (V third unused)
  u16* xb     = (u16*)ws;
  u16* wqkvT  = (u16*)(ws + SZ_XB);
  u16* wprojT = (u16*)(ws + SZ_XB + SZ_WQKV);
  u16* qkv    = (u16*)(ws + SZ_XB + SZ_WQKV + SZ_WPROJ);
  u16* vt     = (u16*)(ws + SZ_XB + SZ_WQKV + SZ_WPROJ + SZ_QKV);  // [64][64][2048] bf16

  cvt_f32_bf16<<<dim3((Bsz * Tseq * Cdim / 4 + 255) / 256), dim3(256), 0, stream>>>(
      x, xb, Bsz * Tseq * Cdim / 4);
  transpose_cvt<<<dim3(3 * Cdim / 32, Cdim / 32), dim3(32, 8), 0, stream>>>(W_qkv, wqkvT, Cdim, 3 * Cdim);
  transpose_cvt<<<dim3(Cdim / 32, Cdim / 32), dim3(32, 8), 0, stream>>>(W_proj, wprojT, Cdim, Cdim);
  gemm_qkv<<<dim3(3 * Cdim / 256, Bsz * Tseq / 256), dim3(512), 0, stream>>>(
      xb, wqkvT, b_qkv, qkv, vt, Bsz * Tseq, 3 * Cdim, Cdim);
  attn_fwd<<<dim3(8, Bsz * Hh), dim3(512), 0, stream>>>(qkv, vt, xb);
  gemm_bt<0><<<dim3(Cdim / 256, Bsz * Tseq / 128), dim3(512), 0, stream>>>(
      xb, wprojT, b_proj, out, nullptr, Bsz * Tseq, Cdim, Cdim);
}

// Round 11
// 161.876 us; speedup vs baseline: 1.1015x; 1.1015x over previous
//
#include <hip/hip_runtime.h>
#include <hip/hip_bf16.h>
#include <cstdint>
#include <cstddef>

#define Bsz 4
#define Tseq 2048
#define Cdim 1024
#define Hh 16
#define Dh 64

typedef unsigned short u16;
typedef __bf16 bfx8 __attribute__((ext_vector_type(8)));
typedef float f32x4 __attribute__((ext_vector_type(4)));
typedef float f32x16 __attribute__((ext_vector_type(16)));
typedef unsigned short u16x8 __attribute__((ext_vector_type(8)));

#define AS1 __attribute__((address_space(1)))
#define AS3 __attribute__((address_space(3)))

// 0.125 (1/sqrt(64)) * log2(e): K pre-scale so softmax runs in exp2 domain
#define QSCALE 0.18033688f

__device__ __forceinline__ u16 f2b(float f) {
  union { float f; unsigned u; } x; x.f = f;
  unsigned r = x.u + 0x7FFFu + ((x.u >> 16) & 1u);
  return (u16)(r >> 16);
}
__device__ __forceinline__ float b2f(u16 b) {
  union { unsigned u; float f; } x; x.u = ((unsigned)b) << 16; return x.f;
}
__device__ __forceinline__ unsigned cvtpk(float lo, float hi) {
  unsigned r;
  asm("v_cvt_pk_bf16_f32 %0, %1, %2" : "=v"(r) : "v"(lo), "v"(hi));
  return r;
}
__device__ __forceinline__ void swap32(unsigned &a, unsigned &b) {
  asm("v_permlane32_swap_b32 %0, %1" : "+v"(a), "+v"(b));
}

// ---------------- fused preprocessing: x->bf16 + both W transposes ----------------
// Grid partition: [0,8192) cvt blocks (256 float4 each, exact cover of 8192x1024),
// [8192,11264) W_qkv transpose 32x32 tiles (96x32), [11264,12288) W_proj (32x32).
// Branch is block-uniform; transposes use the proven tile[32][33] pattern.
__global__ __launch_bounds__(256) void prep_all(const float* __restrict__ x, u16* __restrict__ xb,
                                                const float* __restrict__ Wq, u16* __restrict__ wqkvT,
                                                const float* __restrict__ Wp, u16* __restrict__ wprojT) {
  const int bid = blockIdx.x;
  if (bid < 8192) {
    const int i = bid * 256 + threadIdx.x;
    const float4 v = reinterpret_cast<const float4*>(x)[i];
    ushort4 o;
    o.x = f2b(v.x); o.y = f2b(v.y); o.z = f2b(v.z); o.w = f2b(v.w);
    reinterpret_cast<ushort4*>(xb)[i] = o;
  } else {
    __shared__ float tile[32][33];
    const float* in; u16* out; int Cn, bx, by;
    if (bid < 8192 + 3072) {
      const int b2 = bid - 8192;
      in = Wq; out = wqkvT; Cn = 3072; bx = b2 % 96; by = b2 / 96;
    } else {
      const int b2 = bid - 11264;
      in = Wp; out = wprojT; Cn = 1024; bx = b2 & 31; by = b2 >> 5;
    }
    const int R = 1024;
    const int c0 = bx * 32, r0 = by * 32;
    const int tx = threadIdx.x & 31, ty = threadIdx.x >> 5;
    for (int i = ty; i < 32; i += 8)
      tile[i][tx] = in[(size_t)(r0 + i) * Cn + c0 + tx];
    __syncthreads();
    for (int i = ty; i < 32; i += 8)
      out[(size_t)(c0 + i) * R + r0 + tx] = f2b(tile[tx][i]);
  }
}

// ---------------- bf16 GEMM: C[M,N] = A[M,K] * Bt[N,K]^T + bias ----------------
// r14 PROVEN (166.6us config): ring-3 counted-vmcnt pipeline + split lgkm wait.
// BM=128, BN=256, BK=32, 8 waves (2Mx4N), per-wave 64x64. LDS 72KB -> 2/CU.
template<int MODE>
__global__ __launch_bounds__(512, 4) void gemm_bt(const u16* __restrict__ A, const u16* __restrict__ Bt,
                                                  const float* __restrict__ bias, void* __restrict__ Cout,
                                                  u16* __restrict__ vtout,
                                                  int M, int N, int K) {
  __shared__ __align__(16) u16 Alds[3][4096];   // [slot][64 lines x 64 u16]
  __shared__ __align__(16) u16 Blds[3][8192];   // [slot][128 lines x 64 u16]
  const int tid = threadIdx.x;
  const int lane = tid & 63;
  const int wid = tid >> 6;           // 0..7
  const int nwgx = gridDim.x;         // N/256
  const int nwg = nwgx * gridDim.y;
  int lin = blockIdx.y * nwgx + blockIdx.x;
  lin = (lin & 7) * (nwg >> 3) + (lin >> 3);  // XCD-chunked swizzle (nwg%8==0)
  const int mbase = (lin / nwgx) * 128;
  const int nbase = (lin % nwgx) * 256;
  const int wm = wid & 1, wn = wid >> 1;

  const int sLlow = lane >> 3;
  const int s8 = (lane & 7) ^ sLlow;
  const int srow = 2 * (wid * 8 + sLlow) + (s8 >> 2);
  const int skof = (s8 & 3) * 8;

  const u16* pa  = A  + (size_t)(mbase + srow) * K + skof;
  const u16* pb0 = Bt + (size_t)(nbase + srow) * K + skof;
  const u16* pb1 = pb0 + (size_t)128 * K;

  const int raA = wm * 64 + (lane & 15);
  const int LA = raA >> 1;
  const int pA = ((raA & 1) * 4 + (lane >> 4)) ^ (LA & 7);
  const int aoffw = LA * 64 + pA * 8;
  const int rbB = wn * 64 + (lane & 15);
  const int LB = rbB >> 1;
  const int pB = ((rbB & 1) * 4 + (lane >> 4)) ^ (LB & 7);
  const int boffw = LB * 64 + pB * 8;

  AS3 u16* aldsb = (AS3 u16*)&Alds[0][0];
  AS3 u16* bldsb = (AS3 u16*)&Blds[0][0];

  const f32x4 vzero = {0.f, 0.f, 0.f, 0.f};
  f32x4 acc[4][4];
  #pragma unroll
  for (int i = 0; i < 4; ++i)
    #pragma unroll
    for (int j = 0; j < 4; ++j) acc[i][j] = vzero;

  const int NT = K >> 5;

  auto stage = [&](int slot) {
    __builtin_amdgcn_global_load_lds((AS1 void*)const_cast<u16*>(pa),
                                     (AS3 void*)&Alds[slot][wid * 512], 16, 0, 0);
    __builtin_amdgcn_global_load_lds((AS1 void*)const_cast<u16*>(pb0),
                                     (AS3 void*)&Blds[slot][wid * 512], 16, 0, 0);
    __builtin_amdgcn_global_load_lds((AS1 void*)const_cast<u16*>(pb1),
                                     (AS3 void*)&Blds[slot][4096 + wid * 512], 16, 0, 0);
    pa += 32; pb0 += 32; pb1 += 32;
  };

  stage(0);
  stage(1);
  asm volatile("s_waitcnt vmcnt(3)" ::: "memory");
  __builtin_amdgcn_s_barrier();

  int slot = 0, pf = 2;
  for (int t = 0; t < NT; ++t) {
    if (t + 2 < NT) stage(pf);

    bfx8 af[4], bfv[4];
    {
      AS3 u16* ap = aldsb + slot * 4096 + aoffw;
      AS3 u16* bp = bldsb + slot * 8192 + boffw;
      asm volatile("ds_read_b128 %0, %1"             : "=v"(af[0])  : "v"(ap));
      asm volatile("ds_read_b128 %0, %1 offset:1024" : "=v"(af[1])  : "v"(ap));
      asm volatile("ds_read_b128 %0, %1"             : "=v"(bfv[0]) : "v"(bp));
      asm volatile("ds_read_b128 %0, %1 offset:1024" : "=v"(bfv[1]) : "v"(bp));
      asm volatile("ds_read_b128 %0, %1 offset:2048" : "=v"(bfv[2]) : "v"(bp));
      asm volatile("ds_read_b128 %0, %1 offset:3072" : "=v"(bfv[3]) : "v"(bp));
      asm volatile("ds_read_b128 %0, %1 offset:2048" : "=v"(af[2])  : "v"(ap));
      asm volatile("ds_read_b128 %0, %1 offset:3072" : "=v"(af[3])  : "v"(ap));
    }
    asm volatile("s_waitcnt lgkmcnt(2)" ::: "memory");
    __builtin_amdgcn_sched_barrier(0);

    __builtin_amdgcn_s_setprio(1);
    #pragma unroll
    for (int mf = 0; mf < 2; ++mf)
      #pragma unroll
      for (int nf = 0; nf < 4; ++nf)
        acc[mf][nf] = __builtin_amdgcn_mfma_f32_16x16x32_bf16(af[mf], bfv[nf], acc[mf][nf], 0, 0, 0);
    __builtin_amdgcn_s_setprio(0);

    asm volatile("s_waitcnt lgkmcnt(0)" ::: "memory");
    __builtin_amdgcn_sched_barrier(0);

    __builtin_amdgcn_s_setprio(1);
    #pragma unroll
    for (int mf = 2; mf < 4; ++mf)
      #pragma unroll
      for (int nf = 0; nf < 4; ++nf)
        acc[mf][nf] = __builtin_amdgcn_mfma_f32_16x16x32_bf16(af[mf], bfv[nf], acc[mf][nf], 0, 0, 0);
    __builtin_amdgcn_s_setprio(0);

    if (t + 2 < NT)      { asm volatile("s_waitcnt vmcnt(3)" ::: "memory"); }
    else if (t + 1 < NT) { asm volatile("s_waitcnt vmcnt(0)" ::: "memory"); }
    if (t + 1 < NT) __builtin_amdgcn_s_barrier();

    slot = (slot == 2) ? 0 : slot + 1;
    pf   = (pf == 2) ? 0 : pf + 1;
  }

  float bv[4];
  #pragma unroll
  for (int nf = 0; nf < 4; ++nf) bv[nf] = bias[nbase + wn * 64 + nf * 16 + (lane & 15)];
  #pragma unroll
  for (int mf = 0; mf < 4; ++mf) {
    #pragma unroll
    for (int nf = 0; nf < 4; ++nf) {
      const int r0 = mbase + wm * 64 + mf * 16 + (lane >> 4) * 4;
      const int c  = nbase + wn * 64 + nf * 16 + (lane & 15);
      const int cb = nbase + wn * 64 + nf * 16;
      const float cscale = (MODE == 1 && cb >= 1024 && cb < 2048) ? QSCALE : 1.0f;
      float v[4];
      #pragma unroll
      for (int j = 0; j < 4; ++j) v[j] = (acc[mf][nf][j] + bv[nf]) * cscale;
      if (MODE == 1 && cb >= 2048) {
        const int hh = (c - 2048) >> 6, dd = (c - 2048) & 63;
        const int bb = r0 >> 11, tt = r0 & 2047;
        ushort4 pkd;
        pkd.x = f2b(v[0]); pkd.y = f2b(v[1]); pkd.z = f2b(v[2]); pkd.w = f2b(v[3]);
        *reinterpret_cast<ushort4*>(
            &vtout[(((size_t)bb * Hh + hh) * Dh + dd) * Tseq + tt]) = pkd;
      } else {
        #pragma unroll
        for (int j = 0; j < 4; ++j) {
          if (MODE == 1) ((u16*)Cout)[(size_t)(r0 + j) * N + c] = f2b(v[j]);
          else           ((float*)Cout)[(size_t)(r0 + j) * N + c] = v[j];
        }
      }
    }
  }
}

// ---------------- causal flash attention: split-KV 8-wave, swapped-QK^T 32x32 ----------------
// EXACT r2 structure (four times measured 77.6-78.7us). FROZEN.
// FIXED-MAX softmax (m = 0): K pre-scaled by QSCALE.
#define ROWI(r) (((r) & 3) + 8 * ((r) >> 2))
__global__ __launch_bounds__(512, 4) void attn_fwd(const u16* __restrict__ qkv,
                                                   const u16* __restrict__ vt,
                                                   u16* __restrict__ aout) {
  __shared__ __align__(16) u16 Klds[4][64 * 64];   // [kt][d] swizzled, ring buf = tile&3
  __shared__ __align__(16) u16 Vtlds[4][64 * 64];  // [d][kt] swizzled
  const int tid = threadIdx.x;
  const int lane = tid & 63;
  const int wid = tid >> 6;   // 0..7
  const int qg = wid & 3;
  const int half = wid >> 2;  // 0: even tiles, 1: odd tiles
  const int lin = blockIdx.y * gridDim.x + blockIdx.x;  // 0..511
  const int bh = (lin & 7) * 8 + ((lin >> 3) & 7);
  const int qpair = lin >> 6;  // 0..7
  const int b = bh >> 4, h = bh & 15;
  const int hi4 = (lane & 32) >> 3;

  const int stg_row = lane >> 3;
  const int stg_srcslot = (lane & 7) ^ (stg_row & 7);

  const u16* gkbase = qkv + ((size_t)b * Tseq + wid * 8 + stg_row) * 3072
                      + 1024 + h * 64 + stg_srcslot * 8;
  const u16* gvbase = vt + ((size_t)bh * Dh + wid * 8 + stg_row) * Tseq + stg_srcslot * 8;

  float* Olds = reinterpret_cast<float*>(&Klds[0][0]);   // [qg][32r][64lane]
  float* Llds = reinterpret_cast<float*>(&Vtlds[0][0]);  // [qg][64lane]

  #pragma unroll 1
  for (int pass = 0; pass < 2; ++pass) {
    const int qtile = pass ? qpair : (15 - qpair);
    const int qwb = qtile * 128 + qg * 32;
    const int ntiles = qtile * 2 + 2;  // always even

    bfx8 qf[4];
    {
      const int qrow = qwb + (lane & 31);
      #pragma unroll
      for (int c = 0; c < 4; ++c) {
        const u16* src = qkv + (size_t)(b * Tseq + qrow) * 3072 + h * 64 + c * 16 + (hi4 << 1);
        qf[c] = *reinterpret_cast<const bfx8*>(src);
      }
    }

    float l_r = 0.f;
    f32x16 o0, o1;
    #pragma unroll
    for (int r = 0; r < 16; ++r) { o0[r] = 0.f; o1[r] = 0.f; }

    auto stageT = [&](int t) {
      const u16* gk = gkbase + (size_t)t * 64 * 3072;
      const u16* gv = gvbase + t * 64;
      __builtin_amdgcn_global_load_lds((AS1 void*)const_cast<u16*>(gk),
                                       (AS3 void*)&Klds[t & 3][wid * 512], 16, 0, 0);
      __builtin_amdgcn_global_load_lds((AS1 void*)const_cast<u16*>(gv),
                                       (AS3 void*)&Vtlds[t & 3][wid * 512], 16, 0, 0);
    };
    stageT(0);
    stageT(1);
    __syncthreads();

    for (int t = 0; t < ntiles; t += 2) {
      if (t + 2 < ntiles) stageT(t + 2);
      if (t + 3 < ntiles) stageT(t + 3);

      const int tt = t + half;
      const int kb = tt * 64;
      const int buf = tt & 3;
      if (kb <= qwb + 31) {
        f32x16 st0, st1;
        #pragma unroll
        for (int r = 0; r < 16; ++r) { st0[r] = 0.f; st1[r] = 0.f; }
        __builtin_amdgcn_s_setprio(1);
        #pragma unroll
        for (int c = 0; c < 4; ++c) {
          const int row0 = lane & 31;
          const int sl = (c * 2 + (lane >> 5)) ^ (row0 & 7);
          const bfx8 k0 = *reinterpret_cast<const bfx8*>(&Klds[buf][row0 * 64 + sl * 8]);
          const bfx8 k1 = *reinterpret_cast<const bfx8*>(&Klds[buf][(row0 + 32) * 64 + sl * 8]);
          st0 = __builtin_amdgcn_mfma_f32_32x32x16_bf16(k0, qf[c], st0, 0, 0, 0);
          st1 = __builtin_amdgcn_mfma_f32_32x32x16_bf16(k1, qf[c], st1, 0, 0, 0);
        }
        __builtin_amdgcn_s_setprio(0);

        if (kb + 63 > qwb) {
          const int qg_ = qwb + (lane & 31);
          #pragma unroll
          for (int r = 0; r < 16; ++r) {
            const int kt = kb + ROWI(r) + hi4;
            if (kt > qg_) st0[r] = -1e30f;
            if (kt + 32 > qg_) st1[r] = -1e30f;
          }
        }

        float rs = 0.f;
        #pragma unroll
        for (int r = 0; r < 16; ++r) { st0[r] = exp2f(st0[r]); rs += st0[r]; }
        #pragma unroll
        for (int r = 0; r < 16; ++r) { st1[r] = exp2f(st1[r]); rs += st1[r]; }
        rs += __shfl_xor(rs, 32);
        l_r += rs;

        bfx8 pf[4];
        #pragma unroll
        for (int tph = 0; tph < 2; ++tph) {
          #pragma unroll
          for (int c2 = 0; c2 < 2; ++c2) {
            const int rb = c2 * 8;
            float s0 = tph ? st1[rb + 0] : st0[rb + 0], s1 = tph ? st1[rb + 1] : st0[rb + 1];
            float s2 = tph ? st1[rb + 2] : st0[rb + 2], s3 = tph ? st1[rb + 3] : st0[rb + 3];
            float s4 = tph ? st1[rb + 4] : st0[rb + 4], s5 = tph ? st1[rb + 5] : st0[rb + 5];
            float s6 = tph ? st1[rb + 6] : st0[rb + 6], s7 = tph ? st1[rb + 7] : st0[rb + 7];
            unsigned w0 = cvtpk(s0, s1);
            unsigned w2 = cvtpk(s4, s5);
            swap32(w0, w2);
            unsigned w1 = cvtpk(s2, s3);
            unsigned w3 = cvtpk(s6, s7);
            swap32(w1, w3);
            union { unsigned w[4]; bfx8 v; } u;
            u.w[0] = w0; u.w[1] = w1; u.w[2] = w2; u.w[3] = w3;
            pf[tph * 2 + c2] = u.v;
          }
        }

        __builtin_amdgcn_s_setprio(1);
        #pragma unroll
        for (int c4 = 0; c4 < 4; ++c4) {
          const int vrow = lane & 31;
          const int sl = (c4 * 2 + (lane >> 5)) ^ (vrow & 7);
          const bfx8 vf0 = *reinterpret_cast<const bfx8*>(&Vtlds[buf][vrow * 64 + sl * 8]);
          const bfx8 vf1 = *reinterpret_cast<const bfx8*>(&Vtlds[buf][(vrow + 32) * 64 + sl * 8]);
          o0 = __builtin_amdgcn_mfma_f32_32x32x16_bf16(pf[c4], vf0, o0, 0, 0, 0);
          o1 = __builtin_amdgcn_mfma_f32_32x32x16_bf16(pf[c4], vf1, o1, 0, 0, 0);
        }
        __builtin_amdgcn_s_setprio(0);
      }

      __syncthreads();
    }

    if (half == 1) {
      Llds[qg * 64 + lane] = l_r;
      #pragma unroll
      for (int r = 0; r < 16; ++r) {
        Olds[qg * 2048 + r * 64 + lane]        = o0[r];
        Olds[qg * 2048 + (r + 16) * 64 + lane] = o1[r];
      }
    }
    __syncthreads();
    if (half == 0) {
      const float l1 = Llds[qg * 64 + lane];
      const float linv = 1.0f / (l_r + l1);
      #pragma unroll
      for (int r = 0; r < 16; ++r) {
        const int src = ROWI(r) + hi4;
        const float cr = __shfl(linv, src);
        const int q = qwb + src;
        const float v0 = (o0[r] + Olds[qg * 2048 + r * 64 + lane]) * cr;
        const float v1 = (o1[r] + Olds[qg * 2048 + (r + 16) * 64 + lane]) * cr;
        aout[(size_t)(b * Tseq + q) * 1024 + h * 64 + (lane & 31)]      = f2b(v0);
        aout[(size_t)(b * Tseq + q) * 1024 + h * 64 + 32 + (lane & 31)] = f2b(v1);
      }
    }
    __syncthreads();
  }
}

// ---------------- launcher ----------------
extern "C" void kernel_launch(void* const* d_in, const int* in_sizes, int n_in,
                              void* d_out, int out_size, void* d_ws, size_t ws_size,
                              hipStream_t stream) {
  const float* x      = (const float*)d_in[0];
  const float* W_qkv  = (const float*)d_in[1];
  const float* b_qkv  = (const float*)d_in[2];
  const float* W_proj = (const float*)d_in[3];
  const float* b_proj = (const float*)d_in[4];
  float* out = (float*)d_out;

  char* ws = (char*)d_ws;
  const size_t SZ_XB    = 16777216;   // [8192][1024] bf16 (x_bf16, later attn out)
  const size_t SZ_WQKV  = 6291456;    // [3072][1024] bf16
  const size_t SZ_WPROJ = 2097152;    // [1024][1024] bf16
  const size_t SZ_QKV   = 50331648;   // [8192][3072] bf16 (V third unused)
  u16* xb     = (u16*)ws;
  u16* wqkvT  = (u16*)(ws + SZ_XB);
  u16* wprojT = (u16*)(ws + SZ_XB + SZ_WQKV);
  u16* qkv    = (u16*)(ws + SZ_XB + SZ_WQKV + SZ_WPROJ);
  u16* vt     = (u16*)(ws + SZ_XB + SZ_WQKV + SZ_WPROJ + SZ_QKV);  // [64][64][2048] bf16

  prep_all<<<dim3(12288), dim3(256), 0, stream>>>(x, xb, W_qkv, wqkvT, W_proj, wprojT);
  gemm_bt<1><<<dim3(3 * Cdim / 256, Bsz * Tseq / 128), dim3(512), 0, stream>>>(
      xb, wqkvT, b_qkv, qkv, vt, Bsz * Tseq, 3 * Cdim, Cdim);
  attn_fwd<<<dim3(8, Bsz * Hh), dim3(512), 0, stream>>>(qkv, vt, xb);
  gemm_bt<0><<<dim3(Cdim / 256, Bsz * Tseq / 128), dim3(512), 0, stream>>>(
      xb, wprojT, b_proj, out, nullptr, Bsz * Tseq, Cdim, Cdim);
}